// Round 1
// baseline (1629.525 us; speedup 1.0000x reference)
//
#include <hip/hip_runtime.h>
#include <math.h>

#define NTOK 4096
#define DIM 512
#define HEADS 8
#define HD 64
#define ATT_SCALE 0.125f  // 1/sqrt(64)

// ---------------------------------------------------------------------------
// Generic 64x64-tile fp32 GEMM: C[M,Nn] = A[M,K] @ B[K,Nn] + bias (+ epilogue)
// EPI: 0 = bias only, 1 = bias + ReLU, 2 = bias + residual add, 3 = qkv scatter
// Requires M%64==0, Nn%64==0, K%16==0.
// ---------------------------------------------------------------------------
template <int EPI>
__launch_bounds__(256)
__global__ void gemm64(const float* __restrict__ A, const float* __restrict__ B,
                       const float* __restrict__ bias, const float* __restrict__ res,
                       float* __restrict__ C, int M, int Nn, int K)
{
    __shared__ float As[16][68];  // [k][m], padded: 68*4=272 bytes, 16B aligned rows
    __shared__ float Bs[16][68];  // [k][n]

    const int t  = threadIdx.x;
    const int tx = t & 15;
    const int ty = t >> 4;
    const int n0 = blockIdx.x * 64;
    const int m0 = blockIdx.y * 64;

    float acc[4][4];
#pragma unroll
    for (int i = 0; i < 4; ++i)
#pragma unroll
        for (int j = 0; j < 4; ++j) acc[i][j] = 0.0f;

    // A-load indexing: thread t loads A[m0 + (t>>2)][kt + (t&3)*4 .. +3]
    const int arow = t >> 2;
    const int akk  = (t & 3) * 4;
    // B-load indexing: thread t loads B[kt + (t>>4)][n0 + (t&15)*4 .. +3]
    const int brow = t >> 4;
    const int bcol = (t & 15) * 4;

    for (int kt = 0; kt < K; kt += 16) {
        __syncthreads();  // protect LDS from previous iteration's readers
        {
            float4 av = *(const float4*)&A[(size_t)(m0 + arow) * K + kt + akk];
            As[akk + 0][arow] = av.x;
            As[akk + 1][arow] = av.y;
            As[akk + 2][arow] = av.z;
            As[akk + 3][arow] = av.w;
            float4 bv = *(const float4*)&B[(size_t)(kt + brow) * Nn + n0 + bcol];
            *(float4*)&Bs[brow][bcol] = bv;
        }
        __syncthreads();
#pragma unroll
        for (int k = 0; k < 16; ++k) {
            float4 af = *(const float4*)&As[k][ty * 4];
            float4 bf = *(const float4*)&Bs[k][tx * 4];
            float ar[4] = {af.x, af.y, af.z, af.w};
            float br[4] = {bf.x, bf.y, bf.z, bf.w};
#pragma unroll
            for (int i = 0; i < 4; ++i)
#pragma unroll
                for (int j = 0; j < 4; ++j)
                    acc[i][j] = fmaf(ar[i], br[j], acc[i][j]);
        }
    }

    // epilogue
    if (EPI == 3) {
        // qkv scatter: col = g*512 + h*64 + d ; a 64-wide tile sits in one (g,h)
        const int g = n0 >> 9;
        const int h = (n0 >> 6) & 7;
        float* dst = C + (size_t)(g * HEADS + h) * NTOK * HD;
#pragma unroll
        for (int i = 0; i < 4; ++i) {
            const int row = m0 + ty * 4 + i;
            const int c   = tx * 4;  // local d
            float4 v;
            v.x = acc[i][0] + bias[n0 + c + 0];
            v.y = acc[i][1] + bias[n0 + c + 1];
            v.z = acc[i][2] + bias[n0 + c + 2];
            v.w = acc[i][3] + bias[n0 + c + 3];
            *(float4*)&dst[(size_t)row * HD + c] = v;
        }
    } else {
#pragma unroll
        for (int i = 0; i < 4; ++i) {
            const int row = m0 + ty * 4 + i;
            const int col = n0 + tx * 4;
            float4 v;
            v.x = acc[i][0] + bias[col + 0];
            v.y = acc[i][1] + bias[col + 1];
            v.z = acc[i][2] + bias[col + 2];
            v.w = acc[i][3] + bias[col + 3];
            if (EPI == 1) {
                v.x = fmaxf(v.x, 0.0f); v.y = fmaxf(v.y, 0.0f);
                v.z = fmaxf(v.z, 0.0f); v.w = fmaxf(v.w, 0.0f);
            }
            if (EPI == 2) {
                const float4 r = *(const float4*)&res[(size_t)row * Nn + col];
                v.x += r.x; v.y += r.y; v.z += r.z; v.w += r.w;
            }
            *(float4*)&C[(size_t)row * Nn + col] = v;
        }
    }
}

// ---------------------------------------------------------------------------
// Flash attention with dense bias, fp32. One block = one head x 64 queries.
// qkv layout: [3][H][N][64]. out layout: [N][DIM] (heads concatenated).
// ---------------------------------------------------------------------------
__launch_bounds__(256)
__global__ void attn_flash(const float* __restrict__ qkv, const float* __restrict__ bias,
                           float* __restrict__ out)
{
    __shared__ float Qst[64][68];  // [d][q]  (Q transposed)
    __shared__ float KPt[64][68];  // phase 1: [d][kcol] (K transposed); phase 2: [c][r] (P^T)
    __shared__ float Vs[64][68];   // [c][d]

    const int h  = blockIdx.y;
    const int q0 = blockIdx.x * 64;
    const float* Qg = qkv + (size_t)(0 * HEADS + h) * NTOK * HD;
    const float* Kg = qkv + (size_t)(1 * HEADS + h) * NTOK * HD;
    const float* Vg = qkv + (size_t)(2 * HEADS + h) * NTOK * HD;
    const float* Bh = bias + (size_t)h * NTOK * NTOK;

    const int t  = threadIdx.x;
    const int tx = t & 15;
    const int ty = t >> 4;
    const int lr = t >> 4;         // load row helper (0..15)
    const int d4 = (t & 15) * 4;   // load col helper

    // load Q tile transposed
#pragma unroll
    for (int i = 0; i < 4; ++i) {
        const int q = lr + i * 16;
        float4 v = *(const float4*)&Qg[(size_t)(q0 + q) * HD + d4];
        Qst[d4 + 0][q] = v.x; Qst[d4 + 1][q] = v.y;
        Qst[d4 + 2][q] = v.z; Qst[d4 + 3][q] = v.w;
    }

    float m_run[4], l_run[4], o[4][4];
#pragma unroll
    for (int i = 0; i < 4; ++i) {
        m_run[i] = -1e30f; l_run[i] = 0.0f;
#pragma unroll
        for (int j = 0; j < 4; ++j) o[i][j] = 0.0f;
    }

    for (int jt = 0; jt < NTOK / 64; ++jt) {
        const int j0 = jt * 64;
        __syncthreads();  // previous iteration's readers of KPt/Vs done (also covers Qst 1st iter)
        // load K (transposed) and V (natural) chunk
#pragma unroll
        for (int i = 0; i < 4; ++i) {
            const int r = lr + i * 16;
            float4 kv = *(const float4*)&Kg[(size_t)(j0 + r) * HD + d4];
            KPt[d4 + 0][r] = kv.x; KPt[d4 + 1][r] = kv.y;
            KPt[d4 + 2][r] = kv.z; KPt[d4 + 3][r] = kv.w;
            float4 vv = *(const float4*)&Vg[(size_t)(j0 + r) * HD + d4];
            *(float4*)&Vs[r][d4] = vv;
        }
        __syncthreads();

        // S = Q K^T  (outer product over d)
        float s[4][4];
#pragma unroll
        for (int i = 0; i < 4; ++i)
#pragma unroll
            for (int j = 0; j < 4; ++j) s[i][j] = 0.0f;
#pragma unroll 16
        for (int d = 0; d < 64; ++d) {
            float4 af = *(const float4*)&Qst[d][ty * 4];
            float4 bf = *(const float4*)&KPt[d][tx * 4];
            float ar[4] = {af.x, af.y, af.z, af.w};
            float br[4] = {bf.x, bf.y, bf.z, bf.w};
#pragma unroll
            for (int i = 0; i < 4; ++i)
#pragma unroll
                for (int j = 0; j < 4; ++j)
                    s[i][j] = fmaf(ar[i], br[j], s[i][j]);
        }
        // scale + bias
#pragma unroll
        for (int i = 0; i < 4; ++i) {
            float4 bv = *(const float4*)&Bh[(size_t)(q0 + ty * 4 + i) * NTOK + j0 + tx * 4];
            s[i][0] = fmaf(s[i][0], ATT_SCALE, bv.x);
            s[i][1] = fmaf(s[i][1], ATT_SCALE, bv.y);
            s[i][2] = fmaf(s[i][2], ATT_SCALE, bv.z);
            s[i][3] = fmaf(s[i][3], ATT_SCALE, bv.w);
        }

        __syncthreads();  // all reads of KPt-as-K done before overwriting with P^T

        // online softmax per row; row group = 16 consecutive lanes (aligned)
        float pr[4][4];
#pragma unroll
        for (int i = 0; i < 4; ++i) {
            float mx = fmaxf(fmaxf(s[i][0], s[i][1]), fmaxf(s[i][2], s[i][3]));
#pragma unroll
            for (int off = 1; off < 16; off <<= 1) mx = fmaxf(mx, __shfl_xor(mx, off));
            const float mnew  = fmaxf(m_run[i], mx);
            const float alpha = __expf(m_run[i] - mnew);
            m_run[i] = mnew;
            float rs = 0.0f;
#pragma unroll
            for (int j = 0; j < 4; ++j) {
                pr[i][j] = __expf(s[i][j] - mnew);
                rs += pr[i][j];
            }
#pragma unroll
            for (int off = 1; off < 16; off <<= 1) rs += __shfl_xor(rs, off);
            l_run[i] = l_run[i] * alpha + rs;
#pragma unroll
            for (int j = 0; j < 4; ++j) o[i][j] *= alpha;
        }
        // write P^T into KPt: KPt[c][r]
#pragma unroll
        for (int j = 0; j < 4; ++j) {
            float4 pv;
            pv.x = pr[0][j]; pv.y = pr[1][j]; pv.z = pr[2][j]; pv.w = pr[3][j];
            *(float4*)&KPt[tx * 4 + j][ty * 4] = pv;
        }
        __syncthreads();

        // O += P V (outer product over c)
#pragma unroll 16
        for (int c = 0; c < 64; ++c) {
            float4 pf = *(const float4*)&KPt[c][ty * 4];
            float4 vf = *(const float4*)&Vs[c][tx * 4];
            float pp[4] = {pf.x, pf.y, pf.z, pf.w};
            float vv[4] = {vf.x, vf.y, vf.z, vf.w};
#pragma unroll
            for (int i = 0; i < 4; ++i)
#pragma unroll
                for (int j = 0; j < 4; ++j)
                    o[i][j] = fmaf(pp[i], vv[j], o[i][j]);
        }
    }

    // normalize + write out[N][DIM], col = h*64 + d
#pragma unroll
    for (int i = 0; i < 4; ++i) {
        const float inv = 1.0f / l_run[i];
        float4 ov;
        ov.x = o[i][0] * inv; ov.y = o[i][1] * inv;
        ov.z = o[i][2] * inv; ov.w = o[i][3] * inv;
        *(float4*)&out[(size_t)(q0 + ty * 4 + i) * DIM + h * HD + tx * 4] = ov;
    }
}

// ---------------------------------------------------------------------------
// LayerNorm over DIM=512, one block per row, 256 threads x 2 elements.
// ---------------------------------------------------------------------------
__launch_bounds__(256)
__global__ void layernorm_k(const float* __restrict__ in, const float* __restrict__ g,
                            const float* __restrict__ b, float* __restrict__ out)
{
    const int row = blockIdx.x;
    const int t   = threadIdx.x;
    const float* x = in + (size_t)row * DIM;

    float2 v = *(const float2*)&x[t * 2];
    float s  = v.x + v.y;
    float ss = v.x * v.x + v.y * v.y;
#pragma unroll
    for (int off = 32; off > 0; off >>= 1) {
        s  += __shfl_xor(s, off);
        ss += __shfl_xor(ss, off);
    }
    __shared__ float red[8];
    const int wave = t >> 6;
    if ((t & 63) == 0) { red[wave] = s; red[wave + 4] = ss; }
    __syncthreads();
    s  = red[0] + red[1] + red[2] + red[3];
    ss = red[4] + red[5] + red[6] + red[7];

    const float mu  = s * (1.0f / DIM);
    const float var = ss * (1.0f / DIM) - mu * mu;
    const float r   = rsqrtf(var + 1e-5f);

    float2 gg = *(const float2*)&g[t * 2];
    float2 bb = *(const float2*)&b[t * 2];
    float2 ov;
    ov.x = (v.x - mu) * r * gg.x + bb.x;
    ov.y = (v.y - mu) * r * gg.y + bb.y;
    *(float2*)&out[(size_t)row * DIM + t * 2] = ov;
}

// ---------------------------------------------------------------------------
extern "C" void kernel_launch(void* const* d_in, const int* in_sizes, int n_in,
                              void* d_out, int out_size, void* d_ws, size_t ws_size,
                              hipStream_t stream)
{
    const float* x        = (const float*)d_in[0];
    const float* attn_bias= (const float*)d_in[1];
    const float* W_qkv    = (const float*)d_in[2];
    const float* b_qkv    = (const float*)d_in[3];
    const float* W_out    = (const float*)d_in[4];
    const float* b_out    = (const float*)d_in[5];
    const float* W_ffn1   = (const float*)d_in[6];
    const float* b_ffn1   = (const float*)d_in[7];
    const float* W_ffn2   = (const float*)d_in[8];
    const float* b_ffn2   = (const float*)d_in[9];
    const float* ln1_g    = (const float*)d_in[10];
    const float* ln1_b    = (const float*)d_in[11];
    const float* ln2_g    = (const float*)d_in[12];
    const float* ln2_b    = (const float*)d_in[13];
    float* out = (float*)d_out;
    float* ws  = (float*)d_ws;

    // workspace layout (floats), peak 48 MB with reuse:
    float* qkv_t   = ws;             // [0, 24 MB)   3*8*4096*64
    float* attnout = ws + 6291456;   // [24, 32 MB)  4096*512
    float* ffn1buf = ws;             // [0, 32 MB)   reuse (qkv_t+attnout dead)
    float* h_pre   = ws + 8388608;   // [32, 40 MB)
    float* y_pre   = h_pre;          // reuse (h_pre dead after LN1)
    float* hbuf    = ws + 10485760;  // [40, 48 MB)

    const dim3 blk(256);

    // 1) qkv = x @ W_qkv + b_qkv, scattered to [3][H][N][64]
    gemm64<3><<<dim3(24, 64), blk, 0, stream>>>(x, W_qkv, b_qkv, nullptr, qkv_t,
                                                NTOK, 3 * DIM, DIM);
    // 2) flash attention with bias
    attn_flash<<<dim3(NTOK / 64, HEADS), blk, 0, stream>>>(qkv_t, attn_bias, attnout);
    // 3) h_pre = x + attnout @ W_out + b_out
    gemm64<2><<<dim3(8, 64), blk, 0, stream>>>(attnout, W_out, b_out, x, h_pre,
                                               NTOK, DIM, DIM);
    // 4) h = LN1(h_pre)
    layernorm_k<<<NTOK, blk, 0, stream>>>(h_pre, ln1_g, ln1_b, hbuf);
    // 5) ffn1 = relu(h @ W_ffn1 + b_ffn1)
    gemm64<1><<<dim3(32, 64), blk, 0, stream>>>(hbuf, W_ffn1, b_ffn1, nullptr, ffn1buf,
                                                NTOK, 4 * DIM, DIM);
    // 6) y_pre = h + ffn1 @ W_ffn2 + b_ffn2
    gemm64<2><<<dim3(8, 64), blk, 0, stream>>>(ffn1buf, W_ffn2, b_ffn2, hbuf, y_pre,
                                               NTOK, DIM, 4 * DIM);
    // 7) out = LN2(y_pre)
    layernorm_k<<<NTOK, blk, 0, stream>>>(y_pre, ln2_g, ln2_b, out);
}

// Round 3
// 1016.482 us; speedup vs baseline: 1.6031x; 1.6031x over previous
//
#include <hip/hip_runtime.h>
#include <math.h>

#define NTOK 4096
#define DIM 512
#define HEADS 8
#define HD 64

typedef __attribute__((ext_vector_type(8))) short bf16x8;     // 8 bf16 in 4 VGPRs
typedef __attribute__((ext_vector_type(16))) float f32x16;    // 32x32 MFMA acc

__device__ inline unsigned short f2bf(float f) {
    union { float f; unsigned int u; } v; v.f = f;
    unsigned int r = v.u + 0x7FFFu + ((v.u >> 16) & 1u);   // RNE
    return (unsigned short)(r >> 16);
}

// ---------------------------------------------------------------------------
// x (fp32) -> bf16, elementwise
// ---------------------------------------------------------------------------
__global__ void cvt_bf16_k(const float* __restrict__ in, unsigned short* __restrict__ out, int n)
{
    int i = (blockIdx.x * 256 + threadIdx.x) * 8;
    if (i >= n) return;
    float4 a = *(const float4*)&in[i];
    float4 b = *(const float4*)&in[i + 4];
    uint4 o;
    o.x = (unsigned int)f2bf(a.x) | ((unsigned int)f2bf(a.y) << 16);
    o.y = (unsigned int)f2bf(a.z) | ((unsigned int)f2bf(a.w) << 16);
    o.z = (unsigned int)f2bf(b.x) | ((unsigned int)f2bf(b.y) << 16);
    o.w = (unsigned int)f2bf(b.z) | ((unsigned int)f2bf(b.w) << 16);
    *(uint4*)&out[i] = o;
}

// ---------------------------------------------------------------------------
// W [K][N] fp32  ->  Wt [N][K] bf16   (64x64 tiles)
// ---------------------------------------------------------------------------
__launch_bounds__(256)
__global__ void wtrans_k(const float* __restrict__ W, unsigned short* __restrict__ Wt,
                         int K, int N)
{
    __shared__ float Ws[64][68];
    const int n0 = blockIdx.x * 64, k0 = blockIdx.y * 64;
    const int t = threadIdx.x;
    {
        const int r = t >> 2, c = (t & 3) * 16;
#pragma unroll
        for (int i = 0; i < 4; ++i)
            *(float4*)&Ws[r][c + i * 4] = *(const float4*)&W[(size_t)(k0 + r) * N + n0 + c + i * 4];
    }
    __syncthreads();
    const int n = t >> 2, kc = (t & 3) * 16;
    uint4 o0, o1;
    o0.x = (unsigned int)f2bf(Ws[kc + 0][n]) | ((unsigned int)f2bf(Ws[kc + 1][n]) << 16);
    o0.y = (unsigned int)f2bf(Ws[kc + 2][n]) | ((unsigned int)f2bf(Ws[kc + 3][n]) << 16);
    o0.z = (unsigned int)f2bf(Ws[kc + 4][n]) | ((unsigned int)f2bf(Ws[kc + 5][n]) << 16);
    o0.w = (unsigned int)f2bf(Ws[kc + 6][n]) | ((unsigned int)f2bf(Ws[kc + 7][n]) << 16);
    o1.x = (unsigned int)f2bf(Ws[kc + 8][n]) | ((unsigned int)f2bf(Ws[kc + 9][n]) << 16);
    o1.y = (unsigned int)f2bf(Ws[kc + 10][n]) | ((unsigned int)f2bf(Ws[kc + 11][n]) << 16);
    o1.z = (unsigned int)f2bf(Ws[kc + 12][n]) | ((unsigned int)f2bf(Ws[kc + 13][n]) << 16);
    o1.w = (unsigned int)f2bf(Ws[kc + 14][n]) | ((unsigned int)f2bf(Ws[kc + 15][n]) << 16);
    *(uint4*)&Wt[(size_t)(n0 + n) * K + k0 + kc] = o0;
    *(uint4*)&Wt[(size_t)(n0 + n) * K + k0 + kc + 8] = o1;
}

// ---------------------------------------------------------------------------
// V natural [h][tok][64] bf16 -> V_t [h][64][4096] bf16
// ---------------------------------------------------------------------------
__launch_bounds__(256)
__global__ void vtrans_k(const unsigned short* __restrict__ qkv, unsigned short* __restrict__ Vt)
{
    __shared__ unsigned short Ts[64][72];
    const int h = blockIdx.y, t0 = blockIdx.x * 64, t = threadIdx.x;
    const unsigned short* src = qkv + ((size_t)(2 * HEADS + h) * NTOK + t0) * HD;
    {
        const int r = t >> 2, c = (t & 3) * 16;
        *(uint4*)&Ts[r][c]     = *(const uint4*)&src[r * HD + c];
        *(uint4*)&Ts[r][c + 8] = *(const uint4*)&src[r * HD + c + 8];
    }
    __syncthreads();
    const int d = t >> 2, tc = (t & 3) * 16;
    uint4 o0, o1;
    o0.x = (unsigned int)Ts[tc + 0][d] | ((unsigned int)Ts[tc + 1][d] << 16);
    o0.y = (unsigned int)Ts[tc + 2][d] | ((unsigned int)Ts[tc + 3][d] << 16);
    o0.z = (unsigned int)Ts[tc + 4][d] | ((unsigned int)Ts[tc + 5][d] << 16);
    o0.w = (unsigned int)Ts[tc + 6][d] | ((unsigned int)Ts[tc + 7][d] << 16);
    o1.x = (unsigned int)Ts[tc + 8][d] | ((unsigned int)Ts[tc + 9][d] << 16);
    o1.y = (unsigned int)Ts[tc + 10][d] | ((unsigned int)Ts[tc + 11][d] << 16);
    o1.z = (unsigned int)Ts[tc + 12][d] | ((unsigned int)Ts[tc + 13][d] << 16);
    o1.w = (unsigned int)Ts[tc + 14][d] | ((unsigned int)Ts[tc + 15][d] << 16);
    *(uint4*)&Vt[((size_t)h * HD + d) * NTOK + t0 + tc] = o0;
    *(uint4*)&Vt[((size_t)h * HD + d) * NTOK + t0 + tc + 8] = o1;
}

// ---------------------------------------------------------------------------
// bf16 MFMA GEMM: C[M,Nn] = A[M,K] @ Bt[Nn,K]^T + bias (+ epilogue)
// EPI: 0 = qkv scatter (bf16 out), 1 = ReLU (bf16 out), 2 = +res (fp32 out)
// Tile: 128 x (64*NT); 4 waves (2x2), each wave 64 x (32*NT); BK=32.
// ---------------------------------------------------------------------------
template <int EPI, int NT>
__launch_bounds__(256)
__global__ void gemm_bf(const unsigned short* __restrict__ A, const unsigned short* __restrict__ Bt,
                        const float* __restrict__ bias, const float* __restrict__ res,
                        void* __restrict__ C, int M, int Nn, int K)
{
    constexpr int BN = 64 * NT;
    __shared__ unsigned short As[128 * 40];   // row stride 40 elem (80B): conflict-free b128
    __shared__ unsigned short Bs[BN * 40];

    const int t = threadIdx.x;
    const int w = t >> 6, lane = t & 63, l31 = lane & 31, h5 = lane >> 5;
    const int wm = w & 1, wn = w >> 1;
    const int m0 = blockIdx.y * 128, n0 = blockIdx.x * BN;

    f32x16 acc[2][NT];
#pragma unroll
    for (int mt = 0; mt < 2; ++mt)
#pragma unroll
        for (int nt = 0; nt < NT; ++nt)
#pragma unroll
            for (int r = 0; r < 16; ++r) acc[mt][nt][r] = 0.0f;

    const int am = t >> 1, ac = (t & 1) * 16;         // A: row, col-chunk
    for (int kt = 0; kt < K; kt += 32) {
        uint4 a0 = *(const uint4*)&A[(size_t)(m0 + am) * K + kt + ac];
        uint4 a1 = *(const uint4*)&A[(size_t)(m0 + am) * K + kt + ac + 8];
        uint4 b0, b1;
        if (NT == 2) {
            b0 = *(const uint4*)&Bt[(size_t)(n0 + (t >> 1)) * K + kt + (t & 1) * 16];
            b1 = *(const uint4*)&Bt[(size_t)(n0 + (t >> 1)) * K + kt + (t & 1) * 16 + 8];
        } else {
            b0 = *(const uint4*)&Bt[(size_t)(n0 + (t >> 2)) * K + kt + (t & 3) * 8];
        }
        __syncthreads();   // previous iter's readers done
        *(uint4*)&As[am * 40 + ac] = a0;
        *(uint4*)&As[am * 40 + ac + 8] = a1;
        if (NT == 2) {
            *(uint4*)&Bs[(t >> 1) * 40 + (t & 1) * 16] = b0;
            *(uint4*)&Bs[(t >> 1) * 40 + (t & 1) * 16 + 8] = b1;
        } else {
            *(uint4*)&Bs[(t >> 2) * 40 + (t & 3) * 8] = b0;
        }
        __syncthreads();
#pragma unroll
        for (int kk = 0; kk < 32; kk += 16) {
            bf16x8 af[2], bf[NT];
#pragma unroll
            for (int mt = 0; mt < 2; ++mt)
                af[mt] = *(const bf16x8*)&As[(wm * 64 + mt * 32 + l31) * 40 + kk + 8 * h5];
#pragma unroll
            for (int nt = 0; nt < NT; ++nt)
                bf[nt] = *(const bf16x8*)&Bs[(wn * 32 * NT + nt * 32 + l31) * 40 + kk + 8 * h5];
#pragma unroll
            for (int mt = 0; mt < 2; ++mt)
#pragma unroll
                for (int nt = 0; nt < NT; ++nt)
                    acc[mt][nt] = __builtin_amdgcn_mfma_f32_32x32x16_bf16(af[mt], bf[nt], acc[mt][nt], 0, 0, 0);
        }
    }

#pragma unroll
    for (int mt = 0; mt < 2; ++mt)
#pragma unroll
        for (int nt = 0; nt < NT; ++nt) {
            const int col = n0 + wn * 32 * NT + nt * 32 + l31;
            const float bv = bias[col];
#pragma unroll
            for (int r = 0; r < 16; ++r) {
                const int row = m0 + wm * 64 + mt * 32 + (r & 3) + 8 * (r >> 2) + 4 * h5;
                float v = acc[mt][nt][r] + bv;
                if (EPI == 0) {
                    const int g = col >> 9, hh = (col >> 6) & 7, d = col & 63;
                    ((unsigned short*)C)[(((size_t)g * HEADS + hh) * NTOK + row) * HD + d] = f2bf(v);
                } else if (EPI == 1) {
                    ((unsigned short*)C)[(size_t)row * Nn + col] = f2bf(fmaxf(v, 0.0f));
                } else {
                    ((float*)C)[(size_t)row * Nn + col] = v + res[(size_t)row * Nn + col];
                }
            }
        }
}

// ---------------------------------------------------------------------------
// Flash attention, bf16 MFMA. Block = 128 thr (2 waves), 64 queries x 1 head.
// qkv bf16 [3][H][N][64]; Vt bf16 [H][64][N]; bias fp32 [H][N][N];
// out bf16 [N][DIM]. Q is pre-scaled by 1/8 during staging (exact in bf16).
// ---------------------------------------------------------------------------
__launch_bounds__(128)
__global__ void attn_bf(const unsigned short* __restrict__ qkv, const unsigned short* __restrict__ Vt,
                        const float* __restrict__ bias, unsigned short* __restrict__ outbf)
{
    __shared__ unsigned short Qs[64 * 72];   // [q][d]   stride 72 (144B) -> b128 conflict-free
    __shared__ unsigned short Ks[64 * 72];   // [key][d]
    __shared__ unsigned short Vs[64 * 72];   // [d][key]
    __shared__ unsigned short Ps[64 * 72];   // [q][key]

    const int h = blockIdx.y, q0 = blockIdx.x * 64;
    const int t = threadIdx.x, w = t >> 6, lane = t & 63, l31 = lane & 31, h5 = lane >> 5;
    const unsigned short* Qg = qkv + (size_t)(0 * HEADS + h) * NTOK * HD;
    const unsigned short* Kg = qkv + (size_t)(1 * HEADS + h) * NTOK * HD;
    const unsigned short* Vg = Vt + (size_t)h * HD * NTOK;
    const float* Bh = bias + (size_t)h * NTOK * NTOK;

    // stage Q, scaled by 0.125 (exponent shift: exact)
    {
        const int r = t & 63, cw = (t >> 6) * 32;
#pragma unroll
        for (int i = 0; i < 4; ++i) {
            uint4 v = *(const uint4*)&Qg[(size_t)(q0 + r) * HD + cw + i * 8];
            unsigned int* pw = (unsigned int*)&v;
#pragma unroll
            for (int j = 0; j < 4; ++j) {
                float lo = __uint_as_float((pw[j] & 0xffffu) << 16) * 0.125f;
                float hi = __uint_as_float(pw[j] & 0xffff0000u) * 0.125f;
                pw[j] = (unsigned int)f2bf(lo) | ((unsigned int)f2bf(hi) << 16);
            }
            *(uint4*)&Qs[r * 72 + cw + i * 8] = v;
        }
    }

    const float* bbase = Bh + (size_t)(q0 + w * 32 + 4 * h5) * NTOK + l31;

    f32x16 o0, o1;
    float mrun[16], lrun[16];
#pragma unroll
    for (int r = 0; r < 16; ++r) { o0[r] = 0.0f; o1[r] = 0.0f; mrun[r] = -1e30f; lrun[r] = 0.0f; }

    for (int j0 = 0; j0 < NTOK; j0 += 64) {
        // ---- global loads (K, V chunk + bias tile) into registers ----
        const int sr = t & 63, cw = (t >> 6) * 32;
        uint4 kv[4], vv[4];
#pragma unroll
        for (int i = 0; i < 4; ++i) {
            kv[i] = *(const uint4*)&Kg[(size_t)(j0 + sr) * HD + cw + i * 8];
            vv[i] = *(const uint4*)&Vg[(size_t)sr * NTOK + j0 + cw + i * 8];
        }
        float br[2][16];
#pragma unroll
        for (int r = 0; r < 16; ++r) {
            const int rowoff = ((r & 3) + 8 * (r >> 2)) * NTOK;
            br[0][r] = bbase[rowoff + j0];
            br[1][r] = bbase[rowoff + j0 + 32];
        }
        __syncthreads();   // all readers of Ks/Vs (prev chunk PV) done
#pragma unroll
        for (int i = 0; i < 4; ++i) {
            *(uint4*)&Ks[sr * 72 + cw + i * 8] = kv[i];
            *(uint4*)&Vs[sr * 72 + cw + i * 8] = vv[i];
        }
        __syncthreads();   // staging visible

        // ---- S = Q K^T ----
        f32x16 s0, s1;
#pragma unroll
        for (int r = 0; r < 16; ++r) { s0[r] = 0.0f; s1[r] = 0.0f; }
#pragma unroll
        for (int kk = 0; kk < 4; ++kk) {
            bf16x8 aq  = *(const bf16x8*)&Qs[(w * 32 + l31) * 72 + kk * 16 + 8 * h5];
            bf16x8 bk0 = *(const bf16x8*)&Ks[(l31) * 72 + kk * 16 + 8 * h5];
            bf16x8 bk1 = *(const bf16x8*)&Ks[(32 + l31) * 72 + kk * 16 + 8 * h5];
            s0 = __builtin_amdgcn_mfma_f32_32x32x16_bf16(aq, bk0, s0, 0, 0, 0);
            s1 = __builtin_amdgcn_mfma_f32_32x32x16_bf16(aq, bk1, s1, 0, 0, 0);
        }

        // ---- bias + online softmax (rows live in 32-lane halves) ----
#pragma unroll
        for (int r = 0; r < 16; ++r) {
            const float x0 = s0[r] + br[0][r];
            const float x1 = s1[r] + br[1][r];
            float mx = fmaxf(x0, x1);
#pragma unroll
            for (int off = 1; off < 32; off <<= 1) mx = fmaxf(mx, __shfl_xor(mx, off));
            const float mnew = fmaxf(mrun[r], mx);
            const float al = __expf(mrun[r] - mnew);
            const float p0 = __expf(x0 - mnew);
            const float p1 = __expf(x1 - mnew);
            float rs = p0 + p1;
#pragma unroll
            for (int off = 1; off < 32; off <<= 1) rs += __shfl_xor(rs, off);
            lrun[r] = lrun[r] * al + rs;
            mrun[r] = mnew;
            o0[r] *= al; o1[r] *= al;
            const int prow = w * 32 + (r & 3) + 8 * (r >> 2) + 4 * h5;
            Ps[prow * 72 + l31]      = f2bf(p0);
            Ps[prow * 72 + 32 + l31] = f2bf(p1);
        }
        __syncthreads();   // P visible

        // ---- O += P V ----
#pragma unroll
        for (int kk = 0; kk < 4; ++kk) {
            bf16x8 ap  = *(const bf16x8*)&Ps[(w * 32 + l31) * 72 + kk * 16 + 8 * h5];
            bf16x8 bv0 = *(const bf16x8*)&Vs[(l31) * 72 + kk * 16 + 8 * h5];
            bf16x8 bv1 = *(const bf16x8*)&Vs[(32 + l31) * 72 + kk * 16 + 8 * h5];
            o0 = __builtin_amdgcn_mfma_f32_32x32x16_bf16(ap, bv0, o0, 0, 0, 0);
            o1 = __builtin_amdgcn_mfma_f32_32x32x16_bf16(ap, bv1, o1, 0, 0, 0);
        }
    }

    // ---- epilogue: normalize, write bf16 [N][DIM] ----
#pragma unroll
    for (int r = 0; r < 16; ++r) {
        const float inv = 1.0f / lrun[r];
        const int row = q0 + w * 32 + (r & 3) + 8 * (r >> 2) + 4 * h5;
        outbf[(size_t)row * DIM + h * HD + l31]      = f2bf(o0[r] * inv);
        outbf[(size_t)row * DIM + h * HD + 32 + l31] = f2bf(o1[r] * inv);
    }
}

// ---------------------------------------------------------------------------
// LayerNorm over DIM=512; optional bf16 aux output.
// ---------------------------------------------------------------------------
__launch_bounds__(256)
__global__ void ln_k(const float* __restrict__ in, const float* __restrict__ g,
                     const float* __restrict__ b, float* __restrict__ out,
                     unsigned short* __restrict__ aux_bf)
{
    const int row = blockIdx.x;
    const int t = threadIdx.x;
    const float* x = in + (size_t)row * DIM;

    float2 v = *(const float2*)&x[t * 2];
    float s = v.x + v.y;
    float ss = v.x * v.x + v.y * v.y;
#pragma unroll
    for (int off = 32; off > 0; off >>= 1) {
        s += __shfl_xor(s, off);
        ss += __shfl_xor(ss, off);
    }
    __shared__ float red[8];
    const int wave = t >> 6;
    if ((t & 63) == 0) { red[wave] = s; red[wave + 4] = ss; }
    __syncthreads();
    s = red[0] + red[1] + red[2] + red[3];
    ss = red[4] + red[5] + red[6] + red[7];

    const float mu = s * (1.0f / DIM);
    const float var = ss * (1.0f / DIM) - mu * mu;
    const float r = rsqrtf(var + 1e-5f);

    float2 gg = *(const float2*)&g[t * 2];
    float2 bb = *(const float2*)&b[t * 2];
    float2 ov;
    ov.x = (v.x - mu) * r * gg.x + bb.x;
    ov.y = (v.y - mu) * r * gg.y + bb.y;
    *(float2*)&out[(size_t)row * DIM + t * 2] = ov;
    if (aux_bf)
        ((unsigned int*)aux_bf)[row * (DIM / 2) + t] =
            (unsigned int)f2bf(ov.x) | ((unsigned int)f2bf(ov.y) << 16);
}

// ---------------------------------------------------------------------------
// Workspace layout (float offsets from ws). Verified non-overlapping per phase:
//   Wqkvt   [0,        393216)   1536*512 bf16          (live: all)
//   Woutt   [393216,   524288)   512*512 bf16           (live: all)
//   Wffn1t  [524288,  1048576)   2048*512 bf16          (live: all)
//   Wffn2t  [1048576, 1572864)   512*2048 bf16          (live: all)
//   x_bf    [1572864, 2621440)   4096*512 bf16          (dead after qkv GEMM)
//   qkv_bf  [2621440, 5767168)   3*8*4096*64 bf16       (dead after attn)
//   Vt_bf   [5767168, 6815744)   8*64*4096 bf16         (dead after attn)
//   attnout [6815744, 7864320)   4096*512 bf16          (dead after out-proj)
//   h_pre   [7864320, 9961472)   4096*512 f32           (reused as y_pre)
//   h_f32   [5767168, 7864320)   4096*512 f32  -- reuses Vt+attnout (dead)
//   h_bf    [9961472, 11010048)  4096*512 bf16
//   ffn1_bf [1572864, 5767168)   4096*2048 bf16 -- reuses x_bf+qkv_bf (dead)
// peak = 11,010,048 floats = 44.04 MB
// ---------------------------------------------------------------------------
extern "C" void kernel_launch(void* const* d_in, const int* in_sizes, int n_in,
                              void* d_out, int out_size, void* d_ws, size_t ws_size,
                              hipStream_t stream)
{
    const float* x         = (const float*)d_in[0];
    const float* attn_bias = (const float*)d_in[1];
    const float* W_qkv     = (const float*)d_in[2];
    const float* b_qkv     = (const float*)d_in[3];
    const float* W_out     = (const float*)d_in[4];
    const float* b_out     = (const float*)d_in[5];
    const float* W_ffn1    = (const float*)d_in[6];
    const float* b_ffn1    = (const float*)d_in[7];
    const float* W_ffn2    = (const float*)d_in[8];
    const float* b_ffn2    = (const float*)d_in[9];
    const float* ln1_g     = (const float*)d_in[10];
    const float* ln1_b     = (const float*)d_in[11];
    const float* ln2_g     = (const float*)d_in[12];
    const float* ln2_b     = (const float*)d_in[13];
    float* out = (float*)d_out;
    float* ws  = (float*)d_ws;

    unsigned short* Wqkvt      = (unsigned short*)(ws);
    unsigned short* Woutt      = (unsigned short*)(ws + 393216);
    unsigned short* Wffn1t     = (unsigned short*)(ws + 524288);
    unsigned short* Wffn2t     = (unsigned short*)(ws + 1048576);
    unsigned short* x_bf       = (unsigned short*)(ws + 1572864);
    unsigned short* qkv_bf     = (unsigned short*)(ws + 2621440);
    unsigned short* Vt_bf      = (unsigned short*)(ws + 5767168);
    unsigned short* attnout_bf = (unsigned short*)(ws + 6815744);
    float*          h_pre      = ws + 7864320;
    float*          y_pre      = h_pre;
    float*          h_f32      = ws + 5767168;
    unsigned short* h_bf       = (unsigned short*)(ws + 9961472);
    unsigned short* ffn1_bf    = (unsigned short*)(ws + 1572864);

    cvt_bf16_k<<<dim3(1024), 256, 0, stream>>>(x, x_bf, NTOK * DIM);
    wtrans_k<<<dim3(24, 8), 256, 0, stream>>>(W_qkv, Wqkvt, 512, 1536);
    wtrans_k<<<dim3(8, 8), 256, 0, stream>>>(W_out, Woutt, 512, 512);
    wtrans_k<<<dim3(32, 8), 256, 0, stream>>>(W_ffn1, Wffn1t, 512, 2048);
    wtrans_k<<<dim3(8, 32), 256, 0, stream>>>(W_ffn2, Wffn2t, 2048, 512);

    gemm_bf<0, 2><<<dim3(12, 32), 256, 0, stream>>>(x_bf, Wqkvt, b_qkv, nullptr,
                                                    qkv_bf, NTOK, 1536, 512);
    vtrans_k<<<dim3(64, 8), 256, 0, stream>>>(qkv_bf, Vt_bf);
    attn_bf<<<dim3(64, 8), 128, 0, stream>>>(qkv_bf, Vt_bf, attn_bias, attnout_bf);
    gemm_bf<2, 1><<<dim3(8, 32), 256, 0, stream>>>(attnout_bf, Woutt, b_out, x,
                                                   h_pre, NTOK, 512, 512);
    ln_k<<<NTOK, 256, 0, stream>>>(h_pre, ln1_g, ln1_b, h_f32, h_bf);
    gemm_bf<1, 2><<<dim3(16, 32), 256, 0, stream>>>(h_bf, Wffn1t, b_ffn1, nullptr,
                                                    ffn1_bf, NTOK, 2048, 512);
    gemm_bf<2, 1><<<dim3(8, 32), 256, 0, stream>>>(ffn1_bf, Wffn2t, b_ffn2, h_f32,
                                                   y_pre, NTOK, 512, 2048);
    ln_k<<<NTOK, 256, 0, stream>>>(y_pre, ln2_g, ln2_b, out, nullptr);
}